// Round 8
// baseline (51.276 us; speedup 1.0000x reference)
//
#include <hip/hip_runtime.h>
#include <hip/hip_bf16.h>
#include <stdint.h>

// ---- problem constants ----
#define NF     1044
#define NFP    1152                // fields padded to 36*32
#define FD     9
#define VOCP   (NFP*FD)            // 10368 padded vocab rows
#define NCHUNK 36                  // K chunks of 128 (4 per super-iter, 9 iters)
#define NWPAD  148                 // padded nibble words/row
#define BATCH  16384

typedef float f32x4 __attribute__((ext_vector_type(4)));
typedef short s16x8 __attribute__((ext_vector_type(8)));
typedef short s16x4 __attribute__((ext_vector_type(4)));

static __device__ __forceinline__ unsigned short bf16bits(float v) {
  return __builtin_bit_cast(unsigned short, __float2bfloat16(v));
}

// ---- workspace layout (bytes) ----
#define WS_EMB8 0u                 // bf16 emb8[g][4]: 10368*8 = 82944 (zero for g>=9396)
#define WS_W1T  82944u             // fragment-major bf16 w1*s1: 36*8192 = 294912
#define WS_W2F  377856u            // 2048
#define WS_B1P  379904u            // 128
#define WS_B2P  380032u            // 128; end 380160

// ---- LDS layout (bytes), total 154448 -> 1 block/CU ----
#define L_EMB   0                  // 82944: bf16 emb table (the gather target)
#define L_NIB   82944              // 18944: 32*148*4
#define L_DYN   101888             // 37584: phase A f32 wl[9396]; phase B w1buf 32768 + w2 2048
#define L_PART  139472             // 12288
#define L_LINL  151760             // 128
#define L_H1B   151888             // 2560
#define L_TOT   154448

__global__ __launch_bounds__(256) void k0_setup(
    const float* __restrict__ emb, const float* __restrict__ w1,
    const float* __restrict__ b1, const float* __restrict__ g1,
    const float* __restrict__ be1, const float* __restrict__ w2,
    const float* __restrict__ b2, const float* __restrict__ g2,
    const float* __restrict__ be2, char* __restrict__ ws) {
  const float inv = 1.0f / sqrtf(1.0f + 1e-5f);
  const int idx = blockIdx.x * 256 + threadIdx.x;
  const int total = VOCP + NCHUNK*512 + 1024 + 64;   // 29888
  if (idx >= total) return;
  if (idx < VOCP) {
    int g = idx;
    float4 e = (g < 9396) ? ((const float4*)emb)[g] : make_float4(0.f,0.f,0.f,0.f);
    unsigned lo = (unsigned)bf16bits(e.x) | ((unsigned)bf16bits(e.y) << 16);
    unsigned hi = (unsigned)bf16bits(e.z) | ((unsigned)bf16bits(e.w) << 16);
    *(uint2*)(ws + WS_EMB8 + (size_t)g*8) = make_uint2(lo, hi);
  } else if (idx < VOCP + NCHUNK*512) {
    // one thread per 16-B fragment slot (c,s,kg,h)
    int m = idx - VOCP;
    int h = m & 31, kg = (m >> 5) & 3, s = (m >> 7) & 3, c = m >> 9;
    float s1 = g1[h] * inv;
    unsigned short v16[8];
    #pragma unroll
    for (int i = 0; i < 8; ++i) {
      int k = 128*c + 32*s + ((i < 4) ? (4*kg + i) : (16 + 4*kg + (i - 4)));
      float v = (k < 4176) ? w1[k*32 + h] * s1 : 0.0f;
      v16[i] = bf16bits(v);
    }
    uint4 pk;
    __builtin_memcpy(&pk, v16, 16);
    *(uint4*)(ws + WS_W1T + c*8192 + s*2048 + kg*512 + h*16) = pk;
  } else if (idx < VOCP + NCHUNK*512 + 1024) {
    int m = idx - (VOCP + NCHUNK*512);
    int h = m >> 5, j = m & 31;
    float s2 = g2[j] * inv;
    float v = w2[h*32 + j] * s2;
    int half = h >> 4, kk = h & 15;
    int kg = kk >> 2, e = kk & 3;
    *(__hip_bfloat16*)(ws + WS_W2F + kg*512 + j*16 + (half*4 + e)*2) = __float2bfloat16(v);
  } else {
    int m = idx - (VOCP + NCHUNK*512 + 1024);
    float* b1p = (float*)(ws + WS_B1P);
    float* b2p = (float*)(ws + WS_B2P);
    if (m < 32)      b1p[m]    = b1[m]*(g1[m]*inv) + be1[m];
    else             b2p[m-32] = b2[m-32]*(g2[m-32]*inv) + be2[m-32];
  }
}

static __device__ __forceinline__ unsigned pack8(float4 a, float4 b) {
  float v[8] = {a.x, a.y, a.z, a.w, b.x, b.y, b.z, b.w};
  unsigned pk = 0;
  #pragma unroll
  for (int q = 0; q < 8; ++q) {
    int t = (v[q] > 5.0f) ? 8 : (int)(v[q] + 2.0f);
    pk |= (unsigned)t << (4*q);
  }
  return pk;
}

// fused: hash + lin + gather-GEMM MLP. grid 512 x 512 (8 waves, 32 rows/block)
__global__ __launch_bounds__(512, 2) void k_main(
    const float* __restrict__ state, const float* __restrict__ wlin,
    const float* __restrict__ blin, const char* __restrict__ ws,
    const float* __restrict__ w3g, const float* __restrict__ b3g,
    float* __restrict__ out) {
  __shared__ __align__(16) char smem[L_TOT];
  const int t = threadIdx.x;
  const int l = t & 63, w = t >> 6;
  const int rowbase = blockIdx.x * 32;
  const float bl = blin[0];

  // ---- stage wl (f32 w_lin) + emb8 into LDS ----
  float* wl = (float*)(smem + L_DYN);
  {
    const float4* src = (const float4*)wlin;
    float4* dst = (float4*)wl;
    for (int i = t; i < 2349; i += 512) dst[i] = src[i];
    const uint4* es = (const uint4*)(ws + WS_EMB8);
    uint4* ed = (uint4*)(smem + L_EMB);
    for (int i = t; i < 5184; i += 512) ed[i] = es[i];
  }
  __syncthreads();

  // ---- phase A: barrier-free hash -> nibbles + shuffle-lin (R3-verified) ----
  unsigned* nibL = (unsigned*)(smem + L_NIB);
  float* linL = (float*)(smem + L_LINL);
  const float4 zz = make_float4(0.f, 0.f, 0.f, 0.f);
  #pragma unroll
  for (int b = 0; b < 4; ++b) {
    const int rl = w*4 + b;
    const float4* s4 = (const float4*)(state + (size_t)(rowbase + rl) * 1044);
    float4 a0 = s4[2*l],       c0 = s4[2*l + 1];
    float4 a1 = s4[128 + 2*l], c1 = s4[129 + 2*l];
    float4 ta = (l < 3) ? s4[256 + 2*l] : zz;
    float4 tb = (l < 2) ? s4[257 + 2*l] : zz;
    unsigned pk0 = pack8(a0, c0);
    unsigned pk1 = pack8(a1, c1);
    unsigned pk2 = pack8(ta, tb);               // lanes>=3: 0x22222222 (pad -> v=2 -> zero emb row)
    unsigned* nr = nibL + rl*NWPAD;
    nr[l]      = pk0;
    nr[64 + l] = pk1;
    if (l < 16) nr[128 + l] = pk2;

    float lacc = 0.f;
    #pragma unroll
    for (int j = 0; j < 16; ++j) {
      int src = (l >> 3) + 8 * (j & 7);
      unsigned wv = __shfl((j < 8) ? pk0 : pk1, src, 64);
      int v = (wv >> (4 * (l & 7))) & 15;
      lacc += wl[(l + 64*j) * 9 + v];
    }
    if (l < 20) {                               // fields 1024..1043
      unsigned wv = __shfl(pk2, l >> 3, 64);
      int v = (wv >> (4 * (l & 7))) & 15;
      lacc += wl[(l + 1024) * 9 + v];
    }
    #pragma unroll
    for (int m = 1; m < 64; m <<= 1) lacc += __shfl_xor(lacc, m, 64);
    if (l == 0) linL[rl] = lacc + bl;
  }
  __syncthreads();       // nib/lin visible; wl dead -> region becomes w1buf

  // ---- stage w1 super-chunk 0 + w2 ----
  const uint4* w1g4 = (const uint4*)(ws + WS_W1T);
  uint4* w1buf4 = (uint4*)(smem + L_DYN);
  w1buf4[0*512 + t] = w1g4[0*512 + t];
  w1buf4[1*512 + t] = w1g4[1*512 + t];
  w1buf4[2*512 + t] = w1g4[2*512 + t];
  w1buf4[3*512 + t] = w1g4[3*512 + t];
  if (t < 128) ((uint4*)(smem + L_DYN + 32768))[t] = ((const uint4*)(ws + WS_W2F))[t];
  __syncthreads();

  // ---- phase B: 4-way K-split gather GEMM (emb gathers from LDS) ----
  const int rt = w & 1, kp = w >> 1;
  const int kg = l >> 4, h = l & 15;
  const int sh0 = 8*(kg >> 1);
  const int nibsel = kg & 1;
  const unsigned* nibrow = nibL + (rt*16 + h)*NWPAD;
  const s16x4* E4 = (const s16x4*)(smem + L_EMB);
  f32x4 acc0 = {0.f,0.f,0.f,0.f}, acc1 = {0.f,0.f,0.f,0.f};

  for (int j = 0; j < 9; ++j) {
    uint4 p0, p1, p2, p3;
    const bool more = (j < 8);
    if (more) {
      p0 = w1g4[(j+1)*2048 + 0*512 + t];
      p1 = w1g4[(j+1)*2048 + 1*512 + t];
      p2 = w1g4[(j+1)*2048 + 2*512 + t];
      p3 = w1g4[(j+1)*2048 + 3*512 + t];
    }
    const int c = 4*j + kp;
    uint4 nw = *(const uint4*)(nibrow + 4*c);
    unsigned nwa[4] = {nw.x, nw.y, nw.z, nw.w};
    const char* wb = smem + L_DYN + kp*8192;
    #pragma unroll
    for (int s = 0; s < 4; ++s) {
      unsigned W = nwa[s];
      unsigned bA = (W >> sh0) & 0xFFu;
      unsigned bB = (W >> (sh0 + 16)) & 0xFFu;
      int vA = nibsel ? (int)(bA >> 4) : (int)(bA & 15u);
      int vB = nibsel ? (int)(bB >> 4) : (int)(bB & 15u);
      int F0 = c*32 + s*8 + kg;
      s16x4 e0 = E4[F0*9 + vA];
      s16x4 e1 = E4[(F0+4)*9 + vB];
      s16x8 a = __builtin_shufflevector(e0, e1, 0,1,2,3,4,5,6,7);
      const s16x8* bp = (const s16x8*)(wb + s*2048 + kg*512);
      s16x8 bf0 = bp[h];
      s16x8 bf1 = bp[h + 16];
      acc0 = __builtin_amdgcn_mfma_f32_16x16x32_bf16(a, bf0, acc0, 0, 0, 0);
      acc1 = __builtin_amdgcn_mfma_f32_16x16x32_bf16(a, bf1, acc1, 0, 0, 0);
    }
    __syncthreads();
    if (more) {
      w1buf4[0*512+t] = p0; w1buf4[1*512+t] = p1;
      w1buf4[2*512+t] = p2; w1buf4[3*512+t] = p3;
    }
    __syncthreads();
  }

  // ---- partial combine: kp 1..3 -> kp 0 ----
  float* part = (float*)(smem + L_PART);
  __hip_bfloat16* h1b = (__hip_bfloat16*)(smem + L_H1B);
  if (kp != 0) {
    f32x4* pp = (f32x4*)(part + (((kp-1)*2 + rt)*64 + l)*8);
    pp[0] = acc0; pp[1] = acc1;
  }
  __syncthreads();
  if (kp == 0) {
    #pragma unroll
    for (int q = 0; q < 3; ++q) {
      const f32x4* pp = (const f32x4*)(part + ((q*2 + rt)*64 + l)*8);
      acc0 += pp[0]; acc1 += pp[1];
    }
    const float* b1p = (const float*)(ws + WS_B1P);
    const float bb0 = b1p[h], bb1 = b1p[h + 16];
    #pragma unroll
    for (int reg = 0; reg < 4; ++reg) {
      int r = kg*4 + reg;
      float a0 = acc0[reg] + bb0; a0 = a0 > 0.f ? a0 : 0.f;
      float a1 = acc1[reg] + bb1; a1 = a1 > 0.f ? a1 : 0.f;
      h1b[(rt*16 + r)*40 + h]      = __float2bfloat16(a0);
      h1b[(rt*16 + r)*40 + h + 16] = __float2bfloat16(a1);
    }
  }
  __syncthreads();
  if (kp == 0) {
    s16x4 alo = *(const s16x4*)&h1b[(rt*16 + h)*40 + kg*4];
    s16x4 ahi = *(const s16x4*)&h1b[(rt*16 + h)*40 + 16 + kg*4];
    s16x8 a2 = __builtin_shufflevector(alo, ahi, 0,1,2,3,4,5,6,7);
    const char* w2l = smem + L_DYN + 32768;
    const s16x8* w2p8 = (const s16x8*)(w2l + kg*512);
    s16x8 b20 = w2p8[h];
    s16x8 b21 = w2p8[h + 16];
    f32x4 acc20 = {0.f,0.f,0.f,0.f}, acc21 = {0.f,0.f,0.f,0.f};
    acc20 = __builtin_amdgcn_mfma_f32_16x16x32_bf16(a2, b20, acc20, 0, 0, 0);
    acc21 = __builtin_amdgcn_mfma_f32_16x16x32_bf16(a2, b21, acc21, 0, 0, 0);
    const float* b2p = (const float*)(ws + WS_B2P);
    const float c20 = b2p[h], c21 = b2p[h + 16];
    const float w3a = w3g[h], w3b = w3g[h + 16];
    const float* linL2 = (const float*)(smem + L_LINL);
    const float b3v = b3g[0];
    #pragma unroll
    for (int reg = 0; reg < 4; ++reg) {
      float h2a = acc20[reg] + c20; h2a = h2a > 0.f ? h2a : 0.f;
      float h2b = acc21[reg] + c21; h2b = h2b > 0.f ? h2b : 0.f;
      float p = h2a*w3a + h2b*w3b;
      p += __shfl_xor(p, 1);
      p += __shfl_xor(p, 2);
      p += __shfl_xor(p, 4);
      p += __shfl_xor(p, 8);
      if (h == 0) {
        int rl = rt*16 + kg*4 + reg;
        float x = p + linL2[rl] + b3v;
        out[rowbase + rl] = 1.0f / (1.0f + expf(-x));
      }
    }
  }
}

extern "C" void kernel_launch(void* const* d_in, const int* in_sizes, int n_in,
                              void* d_out, int out_size, void* d_ws, size_t ws_size,
                              hipStream_t stream) {
  const float* state = (const float*)d_in[0];
  const float* wlin  = (const float*)d_in[1];
  const float* blin  = (const float*)d_in[2];
  const float* emb   = (const float*)d_in[3];
  const float* w1    = (const float*)d_in[4];
  const float* b1    = (const float*)d_in[5];
  const float* g1    = (const float*)d_in[6];
  const float* be1   = (const float*)d_in[7];
  const float* w2    = (const float*)d_in[8];
  const float* b2    = (const float*)d_in[9];
  const float* g2    = (const float*)d_in[10];
  const float* be2   = (const float*)d_in[11];
  const float* w3    = (const float*)d_in[12];
  const float* b3    = (const float*)d_in[13];
  char* ws = (char*)d_ws;
  float* out = (float*)d_out;

  hipLaunchKernelGGL(k0_setup, dim3(117), dim3(256), 0, stream,
                     emb, w1, b1, g1, be1, w2, b2, g2, be2, ws);
  hipLaunchKernelGGL(k_main, dim3(512), dim3(512), 0, stream,
                     state, wlin, blin, ws, w3, b3, out);
}

// Round 9
// 51.138 us; speedup vs baseline: 1.0027x; 1.0027x over previous
//
#include <hip/hip_runtime.h>
#include <hip/hip_bf16.h>
#include <stdint.h>

// ---- problem constants ----
#define NF     1044
#define NFP    1152                // fields padded to 36*32
#define FD     9
#define VOCP   (NFP*FD)            // 10368 padded vocab rows
#define NCHUNK 36                  // K chunks of 128
#define NWPAD  148                 // nibble words/row stride (148*4B = 592B, 16B aligned)
#define BATCH  16384

typedef float f32x4 __attribute__((ext_vector_type(4)));
typedef short s16x8 __attribute__((ext_vector_type(8)));
typedef short s16x4 __attribute__((ext_vector_type(4)));

static __device__ __forceinline__ unsigned short bf16bits(float v) {
  return __builtin_bit_cast(unsigned short, __float2bfloat16(v));
}

// ---- workspace layout (bytes) ----
#define WS_EMB8 0u                 // bf16 emb8[g][4]: 10368*8 = 82944 (zero for g>=9396)
#define WS_W1T  82944u             // fragment-major bf16 w1*s1: 36*8192 = 294912
#define WS_W2F  377856u            // 2048
#define WS_B1P  379904u            // 128
#define WS_B2P  380032u            // 128
#define WS_NIB  380160u            // nibbles: 16384 rows * 592B = 9699328
#define WS_LIN  10079488u          // f32 lin[16384] = 65536; end ~10.14 MB

__global__ __launch_bounds__(256) void k0_setup(
    const float* __restrict__ emb, const float* __restrict__ w1,
    const float* __restrict__ b1, const float* __restrict__ g1,
    const float* __restrict__ be1, const float* __restrict__ w2,
    const float* __restrict__ b2, const float* __restrict__ g2,
    const float* __restrict__ be2, char* __restrict__ ws) {
  const float inv = 1.0f / sqrtf(1.0f + 1e-5f);
  const int idx = blockIdx.x * 256 + threadIdx.x;
  const int total = VOCP + NCHUNK*512 + 1024 + 64;   // 29888
  if (idx >= total) return;
  if (idx < VOCP) {
    int g = idx;
    float4 e = (g < 9396) ? ((const float4*)emb)[g] : make_float4(0.f,0.f,0.f,0.f);
    unsigned lo = (unsigned)bf16bits(e.x) | ((unsigned)bf16bits(e.y) << 16);
    unsigned hi = (unsigned)bf16bits(e.z) | ((unsigned)bf16bits(e.w) << 16);
    *(uint2*)(ws + WS_EMB8 + (size_t)g*8) = make_uint2(lo, hi);
  } else if (idx < VOCP + NCHUNK*512) {
    int m = idx - VOCP;
    int h = m & 31, kg = (m >> 5) & 3, s = (m >> 7) & 3, c = m >> 9;
    float s1 = g1[h] * inv;
    unsigned short v16[8];
    #pragma unroll
    for (int i = 0; i < 8; ++i) {
      int k = 128*c + 32*s + ((i < 4) ? (4*kg + i) : (16 + 4*kg + (i - 4)));
      float v = (k < 4176) ? w1[k*32 + h] * s1 : 0.0f;
      v16[i] = bf16bits(v);
    }
    uint4 pk;
    __builtin_memcpy(&pk, v16, 16);
    *(uint4*)(ws + WS_W1T + c*8192 + s*2048 + kg*512 + h*16) = pk;
  } else if (idx < VOCP + NCHUNK*512 + 1024) {
    int m = idx - (VOCP + NCHUNK*512);
    int h = m >> 5, j = m & 31;
    float s2 = g2[j] * inv;
    float v = w2[h*32 + j] * s2;
    int half = h >> 4, kk = h & 15;
    int kg = kk >> 2, e = kk & 3;
    *(__hip_bfloat16*)(ws + WS_W2F + kg*512 + j*16 + (half*4 + e)*2) = __float2bfloat16(v);
  } else {
    int m = idx - (VOCP + NCHUNK*512 + 1024);
    float* b1p = (float*)(ws + WS_B1P);
    float* b2p = (float*)(ws + WS_B2P);
    if (m < 32)      b1p[m]    = b1[m]*(g1[m]*inv) + be1[m];
    else             b2p[m-32] = b2[m-32]*(g2[m-32]*inv) + be2[m-32];
  }
}

static __device__ __forceinline__ unsigned pack8(float4 a, float4 b) {
  float v[8] = {a.x, a.y, a.z, a.w, b.x, b.y, b.z, b.w};
  unsigned pk = 0;
  #pragma unroll
  for (int q = 0; q < 8; ++q) {
    int t = (v[q] > 5.0f) ? 8 : (int)(v[q] + 2.0f);
    pk |= (unsigned)t << (4*q);
  }
  return pk;
}

// kA: hash + lin + nibbles -> ws.  grid 1024 x 256 (4 waves, 16 rows/block, 4 blocks/CU)
__global__ __launch_bounds__(256, 4) void kA_hash(
    const float* __restrict__ state, const float* __restrict__ wlin,
    const float* __restrict__ blin, char* __restrict__ ws) {
  __shared__ float wl[9396];           // 37584 B
  const int t = threadIdx.x;
  {
    const float4* src = (const float4*)wlin;
    float4* dst = (float4*)wl;
    for (int i = t; i < 2349; i += 256) dst[i] = src[i];
  }
  __syncthreads();

  unsigned* nibG = (unsigned*)(ws + WS_NIB);
  float* ling = (float*)(ws + WS_LIN);
  const int l = t & 63, w = t >> 6;
  const float bl = blin[0];
  const float4 zz = make_float4(0.f, 0.f, 0.f, 0.f);
  #pragma unroll
  for (int b = 0; b < 4; ++b) {
    const int row = blockIdx.x*16 + w*4 + b;
    const float4* s4 = (const float4*)(state + (size_t)row * 1044);
    float4 a0 = s4[2*l],       c0 = s4[2*l + 1];
    float4 a1 = s4[128 + 2*l], c1 = s4[129 + 2*l];
    float4 ta = (l < 3) ? s4[256 + 2*l] : zz;
    float4 tb = (l < 2) ? s4[257 + 2*l] : zz;
    unsigned pk0 = pack8(a0, c0);
    unsigned pk1 = pack8(a1, c1);
    unsigned pk2 = pack8(ta, tb);            // lanes>=3: 0x22222222 (pad -> v=2 -> zero emb row)
    unsigned* nr = nibG + (size_t)row * NWPAD;
    nr[l]      = pk0;
    nr[64 + l] = pk1;
    if (l < 16) nr[128 + l] = pk2;

    float lacc = 0.f;
    #pragma unroll
    for (int j = 0; j < 16; ++j) {
      int src = (l >> 3) + 8 * (j & 7);
      unsigned wv = __shfl((j < 8) ? pk0 : pk1, src, 64);
      int v = (wv >> (4 * (l & 7))) & 15;
      lacc += wl[(l + 64*j) * 9 + v];
    }
    if (l < 20) {
      unsigned wv = __shfl(pk2, l >> 3, 64);
      int v = (wv >> (4 * (l & 7))) & 15;
      lacc += wl[(l + 1024) * 9 + v];
    }
    #pragma unroll
    for (int m = 1; m < 64; m <<= 1) lacc += __shfl_xor(lacc, m, 64);
    if (l == 0) ling[row] = lacc + bl;
  }
}

// ---- kB LDS layout (bytes), total 68864 -> 2 blocks/CU ----
#define LB_NIB  0                  // 64*148*4 = 37888
#define LB_W1   37888              // 16384: 2 chunks
#define LB_W2   54272              // 2048
#define LB_PART 56320              // 8192
#define LB_H1B  64512              // 64*40*2 = 5120
#define LB_TOT  69632

// kB: gather-GEMM MLP. grid 256 x 512 (8 waves: rt=w&3 rows, kp=w>>2 K-parity; 64 rows/block)
__global__ __launch_bounds__(512, 4) void kB_mlp(
    const char* __restrict__ ws, const float* __restrict__ w3g,
    const float* __restrict__ b3g, float* __restrict__ out) {
  __shared__ __align__(16) char smem[LB_TOT];
  const int t = threadIdx.x;
  const int l = t & 63, w = t >> 6;
  const int rowbase = blockIdx.x * 64;

  // stage nibbles (64 rows), w1 chunks {0,1}, w2
  unsigned* nibL = (unsigned*)(smem + LB_NIB);
  {
    const uint4* ns = (const uint4*)(ws + WS_NIB + (size_t)rowbase * NWPAD * 4);
    uint4* nd = (uint4*)(smem + LB_NIB);
    for (int i = t; i < 2368; i += 512) nd[i] = ns[i];
  }
  const uint4* w1g4 = (const uint4*)(ws + WS_W1T);
  uint4* w1buf4 = (uint4*)(smem + LB_W1);
  w1buf4[t*2]     = w1g4[t*2];
  w1buf4[t*2 + 1] = w1g4[t*2 + 1];
  if (t < 128) ((uint4*)(smem + LB_W2))[t] = ((const uint4*)(ws + WS_W2F))[t];
  __syncthreads();

  // phase B inner loop (R7-verified mechanics, 2-way K split, 18 iters)
  const int rt = w & 3, kp = w >> 2;
  const int kg = l >> 4, h = l & 15;
  const int sh0 = 8*(kg >> 1);
  const int nibsel = kg & 1;
  const unsigned* nibrow = nibL + (rt*16 + h)*NWPAD;
  const s16x4* E4 = (const s16x4*)(ws + WS_EMB8);
  f32x4 acc0 = {0.f,0.f,0.f,0.f}, acc1 = {0.f,0.f,0.f,0.f};

  for (int j = 0; j < 18; ++j) {
    uint4 p0, p1;
    const bool more = (j < 17);
    if (more) {
      p0 = w1g4[(j+1)*1024 + t*2];
      p1 = w1g4[(j+1)*1024 + t*2 + 1];
    }
    const int c = 2*j + kp;
    uint4 nw = *(const uint4*)(nibrow + 4*c);
    unsigned nwa[4] = {nw.x, nw.y, nw.z, nw.w};
    const char* wb = smem + LB_W1 + kp*8192;
    #pragma unroll
    for (int s = 0; s < 4; ++s) {
      unsigned W = nwa[s];
      unsigned bA = (W >> sh0) & 0xFFu;
      unsigned bB = (W >> (sh0 + 16)) & 0xFFu;
      int vA = nibsel ? (int)(bA >> 4) : (int)(bA & 15u);
      int vB = nibsel ? (int)(bB >> 4) : (int)(bB & 15u);
      int F0 = c*32 + s*8 + kg;
      s16x4 e0 = E4[F0*9 + vA];
      s16x4 e1 = E4[(F0+4)*9 + vB];
      s16x8 a = __builtin_shufflevector(e0, e1, 0,1,2,3,4,5,6,7);
      const s16x8* bp = (const s16x8*)(wb + s*2048 + kg*512);
      s16x8 bf0 = bp[h];
      s16x8 bf1 = bp[h + 16];
      acc0 = __builtin_amdgcn_mfma_f32_16x16x32_bf16(a, bf0, acc0, 0, 0, 0);
      acc1 = __builtin_amdgcn_mfma_f32_16x16x32_bf16(a, bf1, acc1, 0, 0, 0);
    }
    __syncthreads();
    if (more) {
      w1buf4[t*2]     = p0;
      w1buf4[t*2 + 1] = p1;
    }
    __syncthreads();
  }

  // partial combine: kp=1 -> kp=0
  float* part = (float*)(smem + LB_PART);
  __hip_bfloat16* h1b = (__hip_bfloat16*)(smem + LB_H1B);
  if (kp == 1) {
    f32x4* pp = (f32x4*)(part + (rt*64 + l)*8);
    pp[0] = acc0; pp[1] = acc1;
  }
  __syncthreads();
  if (kp == 0) {
    const f32x4* pp = (const f32x4*)(part + (rt*64 + l)*8);
    acc0 += pp[0]; acc1 += pp[1];
    const float* b1p = (const float*)(ws + WS_B1P);
    const float bb0 = b1p[h], bb1 = b1p[h + 16];
    #pragma unroll
    for (int reg = 0; reg < 4; ++reg) {
      int r = kg*4 + reg;
      float a0 = acc0[reg] + bb0; a0 = a0 > 0.f ? a0 : 0.f;
      float a1 = acc1[reg] + bb1; a1 = a1 > 0.f ? a1 : 0.f;
      h1b[(rt*16 + r)*40 + h]      = __float2bfloat16(a0);
      h1b[(rt*16 + r)*40 + h + 16] = __float2bfloat16(a1);
    }
  }
  __syncthreads();
  if (kp == 0) {
    s16x4 alo = *(const s16x4*)&h1b[(rt*16 + h)*40 + kg*4];
    s16x4 ahi = *(const s16x4*)&h1b[(rt*16 + h)*40 + 16 + kg*4];
    s16x8 a2 = __builtin_shufflevector(alo, ahi, 0,1,2,3,4,5,6,7);
    const char* w2l = smem + LB_W2;
    const s16x8* w2p8 = (const s16x8*)(w2l + kg*512);
    s16x8 b20 = w2p8[h];
    s16x8 b21 = w2p8[h + 16];
    f32x4 acc20 = {0.f,0.f,0.f,0.f}, acc21 = {0.f,0.f,0.f,0.f};
    acc20 = __builtin_amdgcn_mfma_f32_16x16x32_bf16(a2, b20, acc20, 0, 0, 0);
    acc21 = __builtin_amdgcn_mfma_f32_16x16x32_bf16(a2, b21, acc21, 0, 0, 0);
    const float* b2p = (const float*)(ws + WS_B2P);
    const float c20 = b2p[h], c21 = b2p[h + 16];
    const float w3a = w3g[h], w3b = w3g[h + 16];
    const float* ling = (const float*)(ws + WS_LIN);
    const float b3v = b3g[0];
    #pragma unroll
    for (int reg = 0; reg < 4; ++reg) {
      float h2a = acc20[reg] + c20; h2a = h2a > 0.f ? h2a : 0.f;
      float h2b = acc21[reg] + c21; h2b = h2b > 0.f ? h2b : 0.f;
      float p = h2a*w3a + h2b*w3b;
      p += __shfl_xor(p, 1);
      p += __shfl_xor(p, 2);
      p += __shfl_xor(p, 4);
      p += __shfl_xor(p, 8);
      if (h == 0) {
        int rl = rt*16 + kg*4 + reg;
        float x = p + ling[rowbase + rl] + b3v;
        out[rowbase + rl] = 1.0f / (1.0f + expf(-x));
      }
    }
  }
}

extern "C" void kernel_launch(void* const* d_in, const int* in_sizes, int n_in,
                              void* d_out, int out_size, void* d_ws, size_t ws_size,
                              hipStream_t stream) {
  const float* state = (const float*)d_in[0];
  const float* wlin  = (const float*)d_in[1];
  const float* blin  = (const float*)d_in[2];
  const float* emb   = (const float*)d_in[3];
  const float* w1    = (const float*)d_in[4];
  const float* b1    = (const float*)d_in[5];
  const float* g1    = (const float*)d_in[6];
  const float* be1   = (const float*)d_in[7];
  const float* w2    = (const float*)d_in[8];
  const float* b2    = (const float*)d_in[9];
  const float* g2    = (const float*)d_in[10];
  const float* be2   = (const float*)d_in[11];
  const float* w3    = (const float*)d_in[12];
  const float* b3    = (const float*)d_in[13];
  char* ws = (char*)d_ws;
  float* out = (float*)d_out;

  hipLaunchKernelGGL(k0_setup, dim3(117), dim3(256), 0, stream,
                     emb, w1, b1, g1, be1, w2, b2, g2, be2, ws);
  hipLaunchKernelGGL(kA_hash, dim3(1024), dim3(256), 0, stream,
                     state, wlin, blin, ws);
  hipLaunchKernelGGL(kB_mlp, dim3(256), dim3(512), 0, stream,
                     ws, w3, b3, out);
}

// Round 10
// 43.569 us; speedup vs baseline: 1.1769x; 1.1737x over previous
//
#include <hip/hip_runtime.h>
#include <hip/hip_bf16.h>
#include <stdint.h>

// ---- problem constants ----
#define NF     1044
#define NFP    1152                // fields padded to 36*32
#define FD     9
#define VOCP   (NFP*FD)            // 10368 padded vocab rows
#define NCHUNK 36                  // K chunks of 128
#define NWPAD  148                 // padded nibble words/row
#define BATCH  16384

typedef float f32x4 __attribute__((ext_vector_type(4)));
typedef short s16x8 __attribute__((ext_vector_type(8)));
typedef short s16x4 __attribute__((ext_vector_type(4)));

static __device__ __forceinline__ unsigned short bf16bits(float v) {
  return __builtin_bit_cast(unsigned short, __float2bfloat16(v));
}

// ---- workspace layout (bytes) ----
#define WS_EMB8 0u                 // bf16 emb8[g][4]: 10368*8 = 82944 (zero for g>=9396)
#define WS_W1T  82944u             // fragment-major bf16 w1*s1: 36*8192 = 294912
#define WS_W2F  377856u            // 2048
#define WS_B1P  379904u            // 128
#define WS_B2P  380032u            // 128; end 380160

// ---- LDS layout (bytes), total 56656 -> 2 blocks/CU ----
#define L_NIB   0                  // 18944: 32*148*4
#define L_DYN   18944              // 37584: phase A f32 wl[9396]; phase B overlay: part 12288 + h1b 2560
#define L_LINL  56528              // 128
#define L_TOT   56656

__global__ __launch_bounds__(256) void k0_setup(
    const float* __restrict__ emb, const float* __restrict__ w1,
    const float* __restrict__ b1, const float* __restrict__ g1,
    const float* __restrict__ be1, const float* __restrict__ w2,
    const float* __restrict__ b2, const float* __restrict__ g2,
    const float* __restrict__ be2, char* __restrict__ ws) {
  const float inv = 1.0f / sqrtf(1.0f + 1e-5f);
  const int idx = blockIdx.x * 256 + threadIdx.x;
  const int total = VOCP + NCHUNK*512 + 1024 + 64;   // 29888
  if (idx >= total) return;
  if (idx < VOCP) {
    int g = idx;
    float4 e = (g < 9396) ? ((const float4*)emb)[g] : make_float4(0.f,0.f,0.f,0.f);
    unsigned lo = (unsigned)bf16bits(e.x) | ((unsigned)bf16bits(e.y) << 16);
    unsigned hi = (unsigned)bf16bits(e.z) | ((unsigned)bf16bits(e.w) << 16);
    *(uint2*)(ws + WS_EMB8 + (size_t)g*8) = make_uint2(lo, hi);
  } else if (idx < VOCP + NCHUNK*512) {
    // one thread per 16-B fragment slot (c,s,kg,h)
    int m = idx - VOCP;
    int h = m & 31, kg = (m >> 5) & 3, s = (m >> 7) & 3, c = m >> 9;
    float s1 = g1[h] * inv;
    unsigned short v16[8];
    #pragma unroll
    for (int i = 0; i < 8; ++i) {
      int k = 128*c + 32*s + ((i < 4) ? (4*kg + i) : (16 + 4*kg + (i - 4)));
      float v = (k < 4176) ? w1[k*32 + h] * s1 : 0.0f;
      v16[i] = bf16bits(v);
    }
    uint4 pk;
    __builtin_memcpy(&pk, v16, 16);
    *(uint4*)(ws + WS_W1T + c*8192 + s*2048 + kg*512 + h*16) = pk;
  } else if (idx < VOCP + NCHUNK*512 + 1024) {
    int m = idx - (VOCP + NCHUNK*512);
    int h = m >> 5, j = m & 31;
    float s2 = g2[j] * inv;
    float v = w2[h*32 + j] * s2;
    int half = h >> 4, kk = h & 15;
    int kg = kk >> 2, e = kk & 3;
    *(__hip_bfloat16*)(ws + WS_W2F + kg*512 + j*16 + (half*4 + e)*2) = __float2bfloat16(v);
  } else {
    int m = idx - (VOCP + NCHUNK*512 + 1024);
    float* b1p = (float*)(ws + WS_B1P);
    float* b2p = (float*)(ws + WS_B2P);
    if (m < 32)      b1p[m]    = b1[m]*(g1[m]*inv) + be1[m];
    else             b2p[m-32] = b2[m-32]*(g2[m-32]*inv) + be2[m-32];
  }
}

static __device__ __forceinline__ unsigned pack8(float4 a, float4 b) {
  float v[8] = {a.x, a.y, a.z, a.w, b.x, b.y, b.z, b.w};
  unsigned pk = 0;
  #pragma unroll
  for (int q = 0; q < 8; ++q) {
    int t = (v[q] > 5.0f) ? 8 : (int)(v[q] + 2.0f);
    pk |= (unsigned)t << (4*q);
  }
  return pk;
}

// fused: hash + lin + gather-GEMM MLP. grid 512 x 512 (8 waves, 32 rows/block, 2 blocks/CU)
// phase B is BARRIER-FREE: B-fragments loaded directly from L2-resident w1t.
__global__ __launch_bounds__(512, 4) void k_main(
    const float* __restrict__ state, const float* __restrict__ wlin,
    const float* __restrict__ blin, const char* __restrict__ ws,
    const float* __restrict__ w3g, const float* __restrict__ b3g,
    float* __restrict__ out) {
  __shared__ __align__(16) char smem[L_TOT];
  const int t = threadIdx.x;
  const int l = t & 63, w = t >> 6;
  const int rowbase = blockIdx.x * 32;
  const float bl = blin[0];

  // ---- stage wl (f32 w_lin table) into LDS for phase A ----
  float* wl = (float*)(smem + L_DYN);
  {
    const float4* src = (const float4*)wlin;
    float4* dst = (float4*)wl;
    for (int i = t; i < 2349; i += 512) dst[i] = src[i];
  }
  __syncthreads();

  // ---- phase A: barrier-free hash -> nibbles + shuffle-lin (R7-verified) ----
  unsigned* nibL = (unsigned*)(smem + L_NIB);
  float* linL = (float*)(smem + L_LINL);
  const float4 zz = make_float4(0.f, 0.f, 0.f, 0.f);
  #pragma unroll
  for (int b = 0; b < 4; ++b) {
    const int rl = w*4 + b;
    const float4* s4 = (const float4*)(state + (size_t)(rowbase + rl) * 1044);
    float4 a0 = s4[2*l],       c0 = s4[2*l + 1];
    float4 a1 = s4[128 + 2*l], c1 = s4[129 + 2*l];
    float4 ta = (l < 3) ? s4[256 + 2*l] : zz;
    float4 tb = (l < 2) ? s4[257 + 2*l] : zz;
    unsigned pk0 = pack8(a0, c0);
    unsigned pk1 = pack8(a1, c1);
    unsigned pk2 = pack8(ta, tb);               // lanes>=3: 0x22222222 (pad -> v=2 -> zero emb row)
    unsigned* nr = nibL + rl*NWPAD;
    nr[l]      = pk0;
    nr[64 + l] = pk1;
    if (l < 16) nr[128 + l] = pk2;

    float lacc = 0.f;
    #pragma unroll
    for (int j = 0; j < 16; ++j) {
      int src = (l >> 3) + 8 * (j & 7);
      unsigned wv = __shfl((j < 8) ? pk0 : pk1, src, 64);
      int v = (wv >> (4 * (l & 7))) & 15;
      lacc += wl[(l + 64*j) * 9 + v];
    }
    if (l < 20) {                               // fields 1024..1043
      unsigned wv = __shfl(pk2, l >> 3, 64);
      int v = (wv >> (4 * (l & 7))) & 15;
      lacc += wl[(l + 1024) * 9 + v];
    }
    #pragma unroll
    for (int m = 1; m < 64; m <<= 1) lacc += __shfl_xor(lacc, m, 64);
    if (l == 0) linL[rl] = lacc + bl;
  }
  __syncthreads();       // nib/lin visible to all waves; wl dead -> overlay region

  // ---- phase B: 4-way K-split gather GEMM, NO barriers, w1 direct from L2 ----
  const int rt = w & 1, kp = w >> 1;
  const int kg = l >> 4, h = l & 15;
  const int sh0 = 8*(kg >> 1);
  const int nibsel = kg & 1;
  const unsigned* nibrow = nibL + (rt*16 + h)*NWPAD;
  const s16x4* E4 = (const s16x4*)(ws + WS_EMB8);
  f32x4 acc0 = {0.f,0.f,0.f,0.f}, acc1 = {0.f,0.f,0.f,0.f};

  for (int j = 0; j < 9; ++j) {
    const int c = 4*j + kp;
    uint4 nw = *(const uint4*)(nibrow + 4*c);
    unsigned nwa[4] = {nw.x, nw.y, nw.z, nw.w};
    const char* wb = ws + WS_W1T + c*8192;      // fragment-major w1, L2-resident
    #pragma unroll
    for (int s = 0; s < 4; ++s) {
      unsigned W = nwa[s];
      unsigned bA = (W >> sh0) & 0xFFu;
      unsigned bB = (W >> (sh0 + 16)) & 0xFFu;
      int vA = nibsel ? (int)(bA >> 4) : (int)(bA & 15u);
      int vB = nibsel ? (int)(bB >> 4) : (int)(bB & 15u);
      int F0 = c*32 + s*8 + kg;
      s16x4 e0 = E4[F0*9 + vA];
      s16x4 e1 = E4[(F0+4)*9 + vB];
      s16x8 a = __builtin_shufflevector(e0, e1, 0,1,2,3,4,5,6,7);
      const s16x8* bp = (const s16x8*)(wb + s*2048 + kg*512);
      s16x8 bf0 = bp[h];
      s16x8 bf1 = bp[h + 16];
      acc0 = __builtin_amdgcn_mfma_f32_16x16x32_bf16(a, bf0, acc0, 0, 0, 0);
      acc1 = __builtin_amdgcn_mfma_f32_16x16x32_bf16(a, bf1, acc1, 0, 0, 0);
    }
  }

  // ---- partial combine: kp 1..3 -> kp 0 (overlay region: part @+0, h1b @+12288) ----
  float* part = (float*)(smem + L_DYN);
  __hip_bfloat16* h1b = (__hip_bfloat16*)(smem + L_DYN + 12288);
  if (kp != 0) {
    f32x4* pp = (f32x4*)(part + (((kp-1)*2 + rt)*64 + l)*8);
    pp[0] = acc0; pp[1] = acc1;
  }
  __syncthreads();
  if (kp == 0) {
    #pragma unroll
    for (int q = 0; q < 3; ++q) {
      const f32x4* pp = (const f32x4*)(part + ((q*2 + rt)*64 + l)*8);
      acc0 += pp[0]; acc1 += pp[1];
    }
    const float* b1p = (const float*)(ws + WS_B1P);
    const float bb0 = b1p[h], bb1 = b1p[h + 16];
    #pragma unroll
    for (int reg = 0; reg < 4; ++reg) {
      int r = kg*4 + reg;
      float a0 = acc0[reg] + bb0; a0 = a0 > 0.f ? a0 : 0.f;
      float a1 = acc1[reg] + bb1; a1 = a1 > 0.f ? a1 : 0.f;
      h1b[(rt*16 + r)*40 + h]      = __float2bfloat16(a0);
      h1b[(rt*16 + r)*40 + h + 16] = __float2bfloat16(a1);
    }
  }
  __syncthreads();
  if (kp == 0) {
    s16x4 alo = *(const s16x4*)&h1b[(rt*16 + h)*40 + kg*4];
    s16x4 ahi = *(const s16x4*)&h1b[(rt*16 + h)*40 + 16 + kg*4];
    s16x8 a2 = __builtin_shufflevector(alo, ahi, 0,1,2,3,4,5,6,7);
    const s16x8* w2p8 = (const s16x8*)(ws + WS_W2F + kg*512);   // direct from L2
    s16x8 b20 = w2p8[h];
    s16x8 b21 = w2p8[h + 16];
    f32x4 acc20 = {0.f,0.f,0.f,0.f}, acc21 = {0.f,0.f,0.f,0.f};
    acc20 = __builtin_amdgcn_mfma_f32_16x16x32_bf16(a2, b20, acc20, 0, 0, 0);
    acc21 = __builtin_amdgcn_mfma_f32_16x16x32_bf16(a2, b21, acc21, 0, 0, 0);
    const float* b2p = (const float*)(ws + WS_B2P);
    const float c20 = b2p[h], c21 = b2p[h + 16];
    const float w3a = w3g[h], w3b = w3g[h + 16];
    const float* linL2 = (const float*)(smem + L_LINL);
    const float b3v = b3g[0];
    #pragma unroll
    for (int reg = 0; reg < 4; ++reg) {
      float h2a = acc20[reg] + c20; h2a = h2a > 0.f ? h2a : 0.f;
      float h2b = acc21[reg] + c21; h2b = h2b > 0.f ? h2b : 0.f;
      float p = h2a*w3a + h2b*w3b;
      p += __shfl_xor(p, 1);
      p += __shfl_xor(p, 2);
      p += __shfl_xor(p, 4);
      p += __shfl_xor(p, 8);
      if (h == 0) {
        int rl = rt*16 + kg*4 + reg;
        float x = p + linL2[rl] + b3v;
        out[rowbase + rl] = 1.0f / (1.0f + expf(-x));
      }
    }
  }
}

extern "C" void kernel_launch(void* const* d_in, const int* in_sizes, int n_in,
                              void* d_out, int out_size, void* d_ws, size_t ws_size,
                              hipStream_t stream) {
  const float* state = (const float*)d_in[0];
  const float* wlin  = (const float*)d_in[1];
  const float* blin  = (const float*)d_in[2];
  const float* emb   = (const float*)d_in[3];
  const float* w1    = (const float*)d_in[4];
  const float* b1    = (const float*)d_in[5];
  const float* g1    = (const float*)d_in[6];
  const float* be1   = (const float*)d_in[7];
  const float* w2    = (const float*)d_in[8];
  const float* b2    = (const float*)d_in[9];
  const float* g2    = (const float*)d_in[10];
  const float* be2   = (const float*)d_in[11];
  const float* w3    = (const float*)d_in[12];
  const float* b3    = (const float*)d_in[13];
  char* ws = (char*)d_ws;
  float* out = (float*)d_out;

  hipLaunchKernelGGL(k0_setup, dim3(117), dim3(256), 0, stream,
                     emb, w1, b1, g1, be1, w2, b2, g2, be2, ws);
  hipLaunchKernelGGL(k_main, dim3(512), dim3(512), 0, stream,
                     state, wlin, blin, ws, w3, b3, out);
}

// Round 11
// 41.249 us; speedup vs baseline: 1.2431x; 1.0562x over previous
//
#include <hip/hip_runtime.h>
#include <hip/hip_bf16.h>
#include <stdint.h>

// ---- problem constants ----
#define NF     1044
#define NFP    1152                // fields padded to 36*32
#define FD     9
#define VOCP   (NFP*FD)            // 10368 padded vocab rows
#define NCHUNK 36                  // K chunks of 128
#define NWPAD  148                 // padded nibble words/row
#define BATCH  16384

typedef float f32x4 __attribute__((ext_vector_type(4)));
typedef short s16x8 __attribute__((ext_vector_type(8)));
typedef short s16x4 __attribute__((ext_vector_type(4)));

static __device__ __forceinline__ unsigned short bf16bits(float v) {
  return __builtin_bit_cast(unsigned short, __float2bfloat16(v));
}

// ---- workspace layout (bytes) ----
#define WS_EMB8 0u                 // bf16 emb8[g][4]: 10368*8 = 82944 (zero for g>=9396)
#define WS_W1T  82944u             // fragment-major bf16 w1*s1: 36*8192 = 294912
#define WS_W2F  377856u            // 2048
#define WS_B1P  379904u            // 128
#define WS_B2P  380032u            // 128
#define WS_WL8  380160u            // bf16 wl[9396] = 18792 (pad to 18816); end 398976

// ---- LDS layout (bytes), total 35760 -> 4 blocks/CU ----
#define L_NIB   0                  // 9472: 16*148*4
#define L_WL    9472               // 18800: bf16 wl table
#define L_PART  28272              // 6144: 3 kp x 64 lanes x 8 f32
#define L_H1B   34416              // 1280: 16*40*2
#define L_LINL  35696              // 64
#define L_TOT   35760

__global__ __launch_bounds__(256) void k0_setup(
    const float* __restrict__ emb, const float* __restrict__ wlin,
    const float* __restrict__ w1, const float* __restrict__ b1,
    const float* __restrict__ g1, const float* __restrict__ be1,
    const float* __restrict__ w2, const float* __restrict__ b2,
    const float* __restrict__ g2, const float* __restrict__ be2,
    char* __restrict__ ws) {
  const float inv = 1.0f / sqrtf(1.0f + 1e-5f);
  const int idx = blockIdx.x * 256 + threadIdx.x;
  const int total = VOCP + NCHUNK*512 + 1024 + 64 + 9396;   // 39284
  if (idx >= total) return;
  if (idx < VOCP) {
    int g = idx;
    float4 e = (g < 9396) ? ((const float4*)emb)[g] : make_float4(0.f,0.f,0.f,0.f);
    unsigned lo = (unsigned)bf16bits(e.x) | ((unsigned)bf16bits(e.y) << 16);
    unsigned hi = (unsigned)bf16bits(e.z) | ((unsigned)bf16bits(e.w) << 16);
    *(uint2*)(ws + WS_EMB8 + (size_t)g*8) = make_uint2(lo, hi);
  } else if (idx < VOCP + NCHUNK*512) {
    // one thread per 16-B fragment slot (c,s,kg,h)
    int m = idx - VOCP;
    int h = m & 31, kg = (m >> 5) & 3, s = (m >> 7) & 3, c = m >> 9;
    float s1 = g1[h] * inv;
    unsigned short v16[8];
    #pragma unroll
    for (int i = 0; i < 8; ++i) {
      int k = 128*c + 32*s + ((i < 4) ? (4*kg + i) : (16 + 4*kg + (i - 4)));
      float v = (k < 4176) ? w1[k*32 + h] * s1 : 0.0f;
      v16[i] = bf16bits(v);
    }
    uint4 pk;
    __builtin_memcpy(&pk, v16, 16);
    *(uint4*)(ws + WS_W1T + c*8192 + s*2048 + kg*512 + h*16) = pk;
  } else if (idx < VOCP + NCHUNK*512 + 1024) {
    int m = idx - (VOCP + NCHUNK*512);
    int h = m >> 5, j = m & 31;
    float s2 = g2[j] * inv;
    float v = w2[h*32 + j] * s2;
    int half = h >> 4, kk = h & 15;
    int kg = kk >> 2, e = kk & 3;
    *(__hip_bfloat16*)(ws + WS_W2F + kg*512 + j*16 + (half*4 + e)*2) = __float2bfloat16(v);
  } else if (idx < VOCP + NCHUNK*512 + 1024 + 64) {
    int m = idx - (VOCP + NCHUNK*512 + 1024);
    float* b1p = (float*)(ws + WS_B1P);
    float* b2p = (float*)(ws + WS_B2P);
    if (m < 32)      b1p[m]    = b1[m]*(g1[m]*inv) + be1[m];
    else             b2p[m-32] = b2[m-32]*(g2[m-32]*inv) + be2[m-32];
  } else {
    int i = idx - (VOCP + NCHUNK*512 + 1024 + 64);
    ((unsigned short*)(ws + WS_WL8))[i] = bf16bits(wlin[i]);
  }
}

static __device__ __forceinline__ unsigned pack8(float4 a, float4 b) {
  float v[8] = {a.x, a.y, a.z, a.w, b.x, b.y, b.z, b.w};
  unsigned pk = 0;
  #pragma unroll
  for (int q = 0; q < 8; ++q) {
    int t = (v[q] > 5.0f) ? 8 : (int)(v[q] + 2.0f);
    pk |= (unsigned)t << (4*q);
  }
  return pk;
}

// fused: hash + lin + gather-GEMM MLP. grid 1024 x 256 (4 waves, 16 rows/block, 4 blocks/CU)
__global__ __launch_bounds__(256, 4) void k_main(
    const float* __restrict__ state, const float* __restrict__ blin,
    const char* __restrict__ ws, const float* __restrict__ w3g,
    const float* __restrict__ b3g, float* __restrict__ out) {
  __shared__ __align__(16) char smem[L_TOT];
  const int t = threadIdx.x;
  const int l = t & 63, w = t >> 6;
  const int rowbase = blockIdx.x * 16;
  const float bl = blin[0];

  // ---- stage bf16 wl table into LDS ----
  {
    const uint4* src = (const uint4*)(ws + WS_WL8);
    uint4* dst = (uint4*)(smem + L_WL);
    for (int i = t; i < 1175; i += 256) dst[i] = src[i];
  }
  __syncthreads();

  // ---- phase A: barrier-free hash -> nibbles; lin gather with deferred reduce ----
  unsigned* nibL = (unsigned*)(smem + L_NIB);
  const __hip_bfloat16* wl = (const __hip_bfloat16*)(smem + L_WL);
  float* linL = (float*)(smem + L_LINL);
  const float4 zz = make_float4(0.f, 0.f, 0.f, 0.f);
  float lacc[4];
  #pragma unroll
  for (int b = 0; b < 4; ++b) {
    const int rl = w*4 + b;
    const float4* s4 = (const float4*)(state + (size_t)(rowbase + rl) * 1044);
    float4 a0 = s4[2*l],       c0 = s4[2*l + 1];
    float4 a1 = s4[128 + 2*l], c1 = s4[129 + 2*l];
    float4 ta = (l < 3) ? s4[256 + 2*l] : zz;
    float4 tb = (l < 2) ? s4[257 + 2*l] : zz;
    unsigned pk0 = pack8(a0, c0);
    unsigned pk1 = pack8(a1, c1);
    unsigned pk2 = pack8(ta, tb);               // lanes>=3: 0x22222222 (pad -> v=2 -> zero emb row)
    unsigned* nr = nibL + rl*NWPAD;
    nr[l]      = pk0;
    nr[64 + l] = pk1;
    if (l < 16) nr[128 + l] = pk2;

    float la = 0.f;
    #pragma unroll
    for (int j = 0; j < 16; ++j) {
      int src = (l >> 3) + 8 * (j & 7);
      unsigned wv = __shfl((j < 8) ? pk0 : pk1, src, 64);
      int v = (wv >> (4 * (l & 7))) & 15;
      la += __bfloat162float(wl[(l + 64*j) * 9 + v]);
    }
    if (l < 20) {                               // fields 1024..1043
      unsigned wv = __shfl(pk2, l >> 3, 64);
      int v = (wv >> (4 * (l & 7))) & 15;
      la += __bfloat162float(wl[(l + 1024) * 9 + v]);
    }
    lacc[b] = la;
  }
  // deferred butterfly: 4 independent chains pipeline through the LDS unit
  #pragma unroll
  for (int m = 1; m < 64; m <<= 1) {
    lacc[0] += __shfl_xor(lacc[0], m, 64);
    lacc[1] += __shfl_xor(lacc[1], m, 64);
    lacc[2] += __shfl_xor(lacc[2], m, 64);
    lacc[3] += __shfl_xor(lacc[3], m, 64);
  }
  if (l == 0) {
    linL[w*4 + 0] = lacc[0] + bl;
    linL[w*4 + 1] = lacc[1] + bl;
    linL[w*4 + 2] = lacc[2] + bl;
    linL[w*4 + 3] = lacc[3] + bl;
  }
  __syncthreads();       // nibbles/lin visible to all waves

  // ---- phase B: 4-way K-split gather GEMM, barrier-free, w1 direct from L2 ----
  const int kp = w;
  const int kg = l >> 4, h = l & 15;
  const int sh0 = 8*(kg >> 1);
  const int nibsel = kg & 1;
  const unsigned* nibrow = nibL + h*NWPAD;
  const s16x4* E4 = (const s16x4*)(ws + WS_EMB8);
  f32x4 acc0 = {0.f,0.f,0.f,0.f}, acc1 = {0.f,0.f,0.f,0.f};

  uint4 nw = *(const uint4*)(nibrow + 4*kp);
  for (int j = 0; j < 9; ++j) {
    const int c = 4*j + kp;
    uint4 nwn = nw;
    if (j < 8) nwn = *(const uint4*)(nibrow + 4*(c + 4));   // prefetch next chunk's nibbles
    unsigned nwa[4] = {nw.x, nw.y, nw.z, nw.w};
    const char* wb = ws + WS_W1T + c*8192;                  // fragment-major w1, L2-resident
    #pragma unroll
    for (int s = 0; s < 4; ++s) {
      unsigned W = nwa[s];
      unsigned bA = (W >> sh0) & 0xFFu;
      unsigned bB = (W >> (sh0 + 16)) & 0xFFu;
      int vA = nibsel ? (int)(bA >> 4) : (int)(bA & 15u);
      int vB = nibsel ? (int)(bB >> 4) : (int)(bB & 15u);
      int F0 = c*32 + s*8 + kg;
      s16x4 e0 = E4[F0*9 + vA];
      s16x4 e1 = E4[(F0+4)*9 + vB];
      s16x8 a = __builtin_shufflevector(e0, e1, 0,1,2,3,4,5,6,7);
      const s16x8* bp = (const s16x8*)(wb + s*2048 + kg*512);
      s16x8 bf0 = bp[h];
      s16x8 bf1 = bp[h + 16];
      acc0 = __builtin_amdgcn_mfma_f32_16x16x32_bf16(a, bf0, acc0, 0, 0, 0);
      acc1 = __builtin_amdgcn_mfma_f32_16x16x32_bf16(a, bf1, acc1, 0, 0, 0);
    }
    nw = nwn;
  }

  // ---- partial combine: kp 1..3 -> kp 0 ----
  float* part = (float*)(smem + L_PART);
  __hip_bfloat16* h1b = (__hip_bfloat16*)(smem + L_H1B);
  if (kp != 0) {
    f32x4* pp = (f32x4*)(part + ((kp-1)*64 + l)*8);
    pp[0] = acc0; pp[1] = acc1;
  }
  __syncthreads();
  if (kp == 0) {
    #pragma unroll
    for (int q = 0; q < 3; ++q) {
      const f32x4* pp = (const f32x4*)(part + (q*64 + l)*8);
      acc0 += pp[0]; acc1 += pp[1];
    }
    const float* b1p = (const float*)(ws + WS_B1P);
    const float bb0 = b1p[h], bb1 = b1p[h + 16];
    #pragma unroll
    for (int reg = 0; reg < 4; ++reg) {
      int r = kg*4 + reg;
      float a0 = acc0[reg] + bb0; a0 = a0 > 0.f ? a0 : 0.f;
      float a1 = acc1[reg] + bb1; a1 = a1 > 0.f ? a1 : 0.f;
      h1b[r*40 + h]      = __float2bfloat16(a0);
      h1b[r*40 + h + 16] = __float2bfloat16(a1);
    }
  }
  __syncthreads();
  if (kp == 0) {
    s16x4 alo = *(const s16x4*)&h1b[h*40 + kg*4];
    s16x4 ahi = *(const s16x4*)&h1b[h*40 + 16 + kg*4];
    s16x8 a2 = __builtin_shufflevector(alo, ahi, 0,1,2,3,4,5,6,7);
    const s16x8* w2p8 = (const s16x8*)(ws + WS_W2F + kg*512);   // direct from L2
    s16x8 b20 = w2p8[h];
    s16x8 b21 = w2p8[h + 16];
    f32x4 acc20 = {0.f,0.f,0.f,0.f}, acc21 = {0.f,0.f,0.f,0.f};
    acc20 = __builtin_amdgcn_mfma_f32_16x16x32_bf16(a2, b20, acc20, 0, 0, 0);
    acc21 = __builtin_amdgcn_mfma_f32_16x16x32_bf16(a2, b21, acc21, 0, 0, 0);
    const float* b2p = (const float*)(ws + WS_B2P);
    const float c20 = b2p[h], c21 = b2p[h + 16];
    const float w3a = w3g[h], w3b = w3g[h + 16];
    const float* linL2 = (const float*)(smem + L_LINL);
    const float b3v = b3g[0];
    #pragma unroll
    for (int reg = 0; reg < 4; ++reg) {
      float h2a = acc20[reg] + c20; h2a = h2a > 0.f ? h2a : 0.f;
      float h2b = acc21[reg] + c21; h2b = h2b > 0.f ? h2b : 0.f;
      float p = h2a*w3a + h2b*w3b;
      p += __shfl_xor(p, 1);
      p += __shfl_xor(p, 2);
      p += __shfl_xor(p, 4);
      p += __shfl_xor(p, 8);
      if (h == 0) {
        int rl = kg*4 + reg;
        float x = p + linL2[rl] + b3v;
        out[rowbase + rl] = 1.0f / (1.0f + expf(-x));
      }
    }
  }
}

extern "C" void kernel_launch(void* const* d_in, const int* in_sizes, int n_in,
                              void* d_out, int out_size, void* d_ws, size_t ws_size,
                              hipStream_t stream) {
  const float* state = (const float*)d_in[0];
  const float* wlin  = (const float*)d_in[1];
  const float* blin  = (const float*)d_in[2];
  const float* emb   = (const float*)d_in[3];
  const float* w1    = (const float*)d_in[4];
  const float* b1    = (const float*)d_in[5];
  const float* g1    = (const float*)d_in[6];
  const float* be1   = (const float*)d_in[7];
  const float* w2    = (const float*)d_in[8];
  const float* b2    = (const float*)d_in[9];
  const float* g2    = (const float*)d_in[10];
  const float* be2   = (const float*)d_in[11];
  const float* w3    = (const float*)d_in[12];
  const float* b3    = (const float*)d_in[13];
  char* ws = (char*)d_ws;
  float* out = (float*)d_out;

  hipLaunchKernelGGL(k0_setup, dim3(154), dim3(256), 0, stream,
                     emb, wlin, w1, b1, g1, be1, w2, b2, g2, be2, ws);
  hipLaunchKernelGGL(k_main, dim3(1024), dim3(256), 0, stream,
                     state, blin, ws, w3, b3, out);
}